// Round 11
// baseline (1572548.828 us; speedup 1.0000x reference)
//
#include <hip/hip_runtime.h>
#include <hip/hip_bf16.h>
#include <stdint.h>

// ---------------------------------------------------------------------------
// Peephole LSTM, SEQ=512, B=64, I=H=1024.  Persistent kernel, 256 blocks.
// Round-20: XCD-LOCAL rowgroups — all state exchange through per-XCD L2.
//  * Mechanism: the 2 exchange legs/step are algorithmically minimal and the
//    per-leg protocol (drain+detect+pull) is minimal (R11/R14/R15/R18); the
//    remaining lever is RT magnitude.  sc0sc1 (L3) RT ~1.5us contended; L2
//    RT ~3-4x faster.  So: pin each rowgroup to ONE XCD and use sc0-only
//    (L2-coherent) comm.
//  * Role assignment: at 1 block/CU with grid==256==#CUs, every CU gets one
//    block => exactly 32 blocks/XCD.  Each block reads XCC_ID (HW-verified,
//    learn_hip m09) and takes slot=atomicAdd(ctr[xcd]).  rowgroup = xcd
//    (xcd<4; XCDs 4-7 exit — latency-bound, idle CUs are free), block owns
//    cols [32*slot, +32) (2 col-tiles), 16 rows.
//  * Comm: h/c payload tiles (1KB: 16 rows x 32 cols bf16) + per-(producer,
//    wave) monotone flags, ALL sc0-only (write-through to local L2; sc0
//    loads bypass L1).  Producer: store -> own-wave vmcnt(0) (L2 ack) ->
//    plain flag store.  Consumer quarter ks: 8 producers, lanes 0-31 poll
//    8x4 flag words, then pull fragments (frag q entirely from producer
//    8ks+q's tile: simpler than R19).
//  * Phase A per wave (K-quarter): x-part 8 frags x 4 gates x 2 tiles
//    (streamed W, A-frag reused 8x), c-part gates w,f, h-part with WH
//    register-pinned (64 frags).  Phase B: 8 frags x 2 tiles, WBo
//    prefetched pre-wait.  Partials in LDS; combines by all 256 threads.
//  * WAR audit (R19 argument carries): collective c-waits(t+1)/h-waits(t+2)
//    span all 32 producers, closing reader-pull(t) < writer-store(t+2/t+1)
//    for both 2-slot rings.  sc_/sx/ldsA/ldsB ordered by the 3 per-step
//    block barriers; per-wave sc_ K-windows are disjoint.
//  * Loud failure: coherence/index error -> absmax fail; role-fill failure
//    -> capped spins (1<<14) -> absmax fail.  Revert target: R19 (5.92ms).
// ---------------------------------------------------------------------------

typedef __attribute__((ext_vector_type(8))) short short8;
typedef __attribute__((ext_vector_type(4))) float f32x4;
typedef __attribute__((ext_vector_type(4))) unsigned int uint4v;

#define OFF_WB   25165824u   // WA: 64cg*4g*96kc*64l*8e bf16
#define OFF_HBF  27262976u   // WB: 2097152
#define OFF_CBF  27525120u   // hbuf: 2 slots * 4grp * 32tile * 1KB = 262144
#define OFF_BAR  27787264u   // cbuf: 262144
#define WS_NEED  27918336u   // bar: hflag@0(2KB), cflag@8192, xcdctr@16384

__device__ __forceinline__ short bfc(float f) {
  __hip_bfloat16 h = __float2bfloat16(f);
  return *reinterpret_cast<short*>(&h);
}
__device__ __forceinline__ unsigned pk2(float a, float b) {
  __hip_bfloat16 ha = __float2bfloat16(a), hb = __float2bfloat16(b);
  unsigned short ua = *reinterpret_cast<unsigned short*>(&ha);
  unsigned short ub = *reinterpret_cast<unsigned short*>(&hb);
  return (unsigned)ua | ((unsigned)ub << 16);
}
__device__ __forceinline__ float sig_fast(float v) {
  return __fdividef(1.f, 1.f + __expf(-v));
}
__device__ __forceinline__ float tanh_fast(float v) {
  float a = fabsf(v);
  float e = __expf(-2.f * a);
  float t = (1.f - e) * __fdividef(1.f, 1.f + e);
  return copysignf(t, v);
}

// ---- sc0-only accesses: L1-bypassing, coherent at the XCD's L2 ----
__device__ __forceinline__ uint4v ldg_l2(const void* p) {
  uint4v r;
  asm volatile("global_load_dwordx4 %0, %1, off sc0" : "=v"(r) : "v"(p));
  return r;
}
__device__ __forceinline__ unsigned poll_l2(const unsigned* p) {
  unsigned r;
  asm volatile("global_load_dword %0, %1, off sc0\n\ts_waitcnt vmcnt(0)"
               : "=v"(r) : "v"(p) : "memory");
  return r;
}
__device__ __forceinline__ void stg_l2(unsigned* p, unsigned v) {
  asm volatile("global_store_dword %0, %1, off sc0" :: "v"(p), "v"(v) : "memory");
}

// ---------------------------------------------------------------------------
// prep: pack weights (R16-identical) + slice-tiled h0 (slot 0) + zero bar.
// WA slot ((cg*4+g)*96+kc)*64+l holds W_g[j=cg*16+(l&15)][kc*32+8*(l>>4)+e]
// WB slot ((cg*4+v)*8+kc)*64+l holds Wo[j][2048 + v*256+kc*32+8*(l>>4)+e].
// h tile (grp,pcol): u32 idx ((grp*32+pcol)<<8) + row*16 + cpr.
// ---------------------------------------------------------------------------
#define Z0 1310720LL
#define Z1 131072LL
#define Z2 32768LL
#define Z3 32768LL

__global__ __launch_bounds__(256)
void prep_kernel(const float* __restrict__ h0, const float* __restrict__ c0,
                 const float* __restrict__ Ww, const float* __restrict__ Wf,
                 const float* __restrict__ Wc, const float* __restrict__ Wo,
                 char* __restrict__ ws) {
  __hip_bfloat16* WA  = (__hip_bfloat16*)ws;
  __hip_bfloat16* WB  = (__hip_bfloat16*)(ws + OFF_WB);
  unsigned*     hbf32 = (unsigned*)(ws + OFF_HBF);   // slot 0
  unsigned*       bar = (unsigned*)(ws + OFF_BAR);

  const long long total = Z0 + Z1 + Z2 + Z3;
  for (long long idx = (long long)blockIdx.x * 256 + threadIdx.x; idx < total;
       idx += (long long)gridDim.x * 256) {
    if (idx < Z0) {
      int l  = (int)(idx & 63);
      int s  = (int)((idx >> 6) % 320);
      int cg = (int)(idx / (320 * 64));
      int g, kc;
      if (s < 96)       { g = 0; kc = s; }
      else if (s < 192) { g = 1; kc = s - 96; }
      else if (s < 256) { g = 2; kc = s - 192; }
      else              { g = 3; kc = s - 256; }
      int j  = cg * 16 + (l & 15);
      int kb = kc * 32 + ((l >> 4) << 3);
      const float* W; int rl;
      if (g == 0)      { W = Ww; rl = 3072; }
      else if (g == 1) { W = Wf; rl = 3072; }
      else if (g == 2) { W = Wc; rl = 2048; }
      else             { W = Wo; rl = 3072; }
      const float* src = W + (size_t)j * rl + kb;
      __hip_bfloat16* dst = WA + ((((size_t)cg * 4 + g) * 96 + kc) * 64 + l) * 8;
#pragma unroll
      for (int e = 0; e < 8; ++e) dst[e] = __float2bfloat16(src[e]);
    } else if (idx < Z0 + Z1) {
      long long q = idx - Z0;
      int l  = (int)(q & 63);
      int kc = (int)((q >> 6) & 7);
      int v  = (int)((q >> 9) & 3);
      int cg = (int)(q >> 11);
      int j  = cg * 16 + (l & 15);
      int k  = 2048 + v * 256 + kc * 32 + ((l >> 4) << 3);
      const float* src = Wo + (size_t)j * 3072 + k;
      __hip_bfloat16* dst = WB + ((((size_t)cg * 4 + v) * 8 + kc) * 64 + l) * 8;
#pragma unroll
      for (int e = 0; e < 8; ++e) dst[e] = __float2bfloat16(src[e]);
    } else if (idx < Z0 + Z1 + Z2) {
      int u  = (int)(idx - (Z0 + Z1));        // pair: R=u>>9 (row), pp=u&511
      int R  = u >> 9, pp = u & 511;
      int grp = R >> 4, row = R & 15;
      int pcol = pp >> 4, cpr = pp & 15;
      const float* hs = h0 + (size_t)R * 1024 + 2 * pp;
      hbf32[(((size_t)grp * 32 + pcol) << 8) + row * 16 + cpr] = pk2(hs[0], hs[1]);
    } else {
      int i = (int)(idx - (Z0 + Z1 + Z2));
      bar[i] = 0u;
    }
  }
}

// ---------------------------------------------------------------------------
// main persistent kernel: roles assigned by XCD at runtime
// ---------------------------------------------------------------------------
__global__ __launch_bounds__(256, 1)
void lstm_kernel(const float* __restrict__ x,  const float* __restrict__ c0,
                 const float* __restrict__ bw, const float* __restrict__ bfg,
                 const float* __restrict__ bc, const float* __restrict__ bo,
                 float* __restrict__ out, char* __restrict__ ws) {
  char*     hT    = ws + OFF_HBF;
  char*     cT    = ws + OFF_CBF;
  unsigned* hflag = (unsigned*)(ws + OFF_BAR);           // ((grp*32+p)*4+w)
  unsigned* cflag = (unsigned*)(ws + OFF_BAR + 8192);
  unsigned* xctr  = (unsigned*)(ws + OFF_BAR + 16384);   // per-XCD slot ctr

  const int tid = threadIdx.x;
  __shared__ int sslot;
  // HW_REG_XCC_ID = 20, offset 0, size 4 bits  [HW-verified: learn_hip m09]
  const unsigned xcd = __builtin_amdgcn_s_getreg(((4 - 1) << 11) | (0 << 6) | 20);
  if (tid == 0) {
    unsigned s = __hip_atomic_fetch_add(xctr + (xcd & 7), 1u,
                                        __ATOMIC_RELAXED, __HIP_MEMORY_SCOPE_AGENT);
    sslot = (int)s;
  }
  __syncthreads();
  const int slot = sslot;
  if (xcd >= 4 || slot >= 32) return;    // XCDs 4-7 / overflow: no role
  const int grp  = (int)xcd;             // rowgroup = this XCD
  const int pcol = slot;                 // 32-col block index (0..31)

  const int l    = tid & 63;
  const int wv   = tid >> 6;             // wave = K-quarter ks
  const int ks   = wv;
  const int col  = l & 15;
  const int kg   = l >> 4;
  const int row16 = col;
  const int srow  = row16 & 7;

  const short8* WAl = (const short8*)ws + l;
  const short8* WBl = (const short8*)(ws + OFF_WB) + l;

  __shared__ __align__(16) char sx[32768];   // x tile  [16][1024] bf16, swizzled
  __shared__ __align__(16) char sc_[32768];  // c tile (carried across steps)
  __shared__ float ldsA[4][4][2][16][17];    // [ks][gate][tile] A-partials
  __shared__ float ldsB[4][2][16][17];       // [ks][tile]       B-partials

  // combine mapping: ALL 256 threads own (crow, 2 cols of this block's 32)
  const int crow = tid >> 4;             // 0..15
  const int cpr  = tid & 15;             // 0..15 (pair)
  const int Tc   = cpr >> 3;             // col-tile of this pair
  const int ci0  = (2 * cpr) & 15, ci1 = ci0 + 1;
  const int coff = ((grp * 16 + crow) << 10) + pcol * 32 + 2 * cpr;
  float c_reg0 = c0[coff], c_reg1 = c0[coff + 1];
  const int jc = pcol * 32 + 2 * cpr;
  const float bw0r = bw[jc],  bw1r = bw[jc + 1];
  const float bf0r = bfg[jc], bf1r = bfg[jc + 1];
  const float bc0r = bc[jc],  bc1r = bc[jc + 1];
  const float bo0r = bo[jc],  bo1r = bo[jc + 1];

  // producer tile bases (within-group; slot index added per step)
  const size_t myTile = ((size_t)grp * 32 + pcol) << 10;   // 1KB tiles
  unsigned* hflagP = hflag + (grp * 32 + pcol) * 4 + wv;
  unsigned* cflagP = cflag + (grp * 32 + pcol) * 4 + wv;

  // ---- startup: stage c0 tile fp32->bf16 -> swizzled sc_ ----
  {
    const float* cs = c0 + (size_t)grp * 16384;
#pragma unroll
    for (int i = 0; i < 8; ++i) {
      int q = i * 256 + tid;
      const float* s = cs + q * 8;
      float4 f0 = *(const float4*)s;
      float4 f1 = *(const float4*)(s + 4);
      short8 v;
      v[0] = bfc(f0.x); v[1] = bfc(f0.y); v[2] = bfc(f0.z); v[3] = bfc(f0.w);
      v[4] = bfc(f1.x); v[5] = bfc(f1.y); v[6] = bfc(f1.z); v[7] = bfc(f1.w);
      int rw = q >> 7, kb = (q & 127) ^ (rw & 7);
      *(short8*)(sc_ + rw * 2048 + (kb << 4)) = v;
    }
  }
  // ---- startup: stage x(0) tile ----
  {
    const float* xs = x + (size_t)grp * 16384;
#pragma unroll
    for (int i = 0; i < 8; ++i) {
      int q = i * 256 + tid;
      const float* s = xs + q * 8;
      float4 f0 = *(const float4*)s;
      float4 f1 = *(const float4*)(s + 4);
      short8 v;
      v[0] = bfc(f0.x); v[1] = bfc(f0.y); v[2] = bfc(f0.z); v[3] = bfc(f0.w);
      v[4] = bfc(f1.x); v[5] = bfc(f1.y); v[6] = bfc(f1.z); v[7] = bfc(f1.w);
      int rw = q >> 7, kb = (q & 127) ^ (rw & 7);
      *(short8*)(sx + rw * 2048 + (kb << 4)) = v;
    }
  }

  // ---- pin h-part weights: 4 gates x 2 tiles x 8 frags (256 VGPR) ----
  short8 WH[4][2][8];
#pragma unroll
  for (int g = 0; g < 4; ++g)
#pragma unroll
    for (int T = 0; T < 2; ++T)
#pragma unroll
      for (int q = 0; q < 8; ++q)
        WH[g][T][q] = WAl[(size_t)(((pcol * 2 + T) * 4 + g) * 96 + 32 + ks * 8 + q) * 64];

  for (int t = 0; t < 512; ++t) {
    const int ps = t & 1;
    const char* hslotR = hT + ((size_t)ps << 17) + (((size_t)grp * 32) << 10);
    unsigned*   hDstW  = (unsigned*)(hT + ((size_t)(ps ^ 1) << 17) + myTile
                                     + crow * 64 + cpr * 4);
    const char* cslotR = cT + ((size_t)(ps ^ 1) << 17) + (((size_t)grp * 32) << 10);
    unsigned*   cDstW  = (unsigned*)(cT + ((size_t)(ps ^ 1) << 17) + myTile
                                     + crow * 64 + cpr * 4);

    __syncthreads();                     // loop-top: orders all LDS reuse

    f32x4 acc[4][2];
#pragma unroll
    for (int g = 0; g < 4; ++g) {
      acc[g][0] = (f32x4){0.f, 0.f, 0.f, 0.f};
      acc[g][1] = (f32x4){0.f, 0.f, 0.f, 0.f};
    }

    // ---- phase A, x part: A-frag loaded once, reused 8x (4g x 2T) ----
#pragma unroll
    for (int q = 0; q < 8; ++q) {
      int kb = 32 * ks + 4 * q + kg;
      short8 a = *(const short8*)(sx + row16 * 2048 + ((kb ^ srow) << 4));
#pragma unroll
      for (int g = 0; g < 4; ++g) {
        acc[g][0] = __builtin_amdgcn_mfma_f32_16x16x32_bf16(a,
            WAl[(size_t)(((pcol * 2 + 0) * 4 + g) * 96 + ks * 8 + q) * 64], acc[g][0], 0, 0, 0);
        acc[g][1] = __builtin_amdgcn_mfma_f32_16x16x32_bf16(a,
            WAl[(size_t)(((pcol * 2 + 1) * 4 + g) * 96 + ks * 8 + q) * 64], acc[g][1], 0, 0, 0);
      }
    }
    // ---- phase A, c part (gates w,f) — sc_ carries c(t-1) ----
#pragma unroll
    for (int q = 0; q < 8; ++q) {
      int kb = 32 * ks + 4 * q + kg;
      short8 a = *(const short8*)(sc_ + row16 * 2048 + ((kb ^ srow) << 4));
#pragma unroll
      for (int g = 0; g < 2; ++g) {
        acc[g][0] = __builtin_amdgcn_mfma_f32_16x16x32_bf16(a,
            WAl[(size_t)(((pcol * 2 + 0) * 4 + g) * 96 + 64 + ks * 8 + q) * 64], acc[g][0], 0, 0, 0);
        acc[g][1] = __builtin_amdgcn_mfma_f32_16x16x32_bf16(a,
            WAl[(size_t)(((pcol * 2 + 1) * 4 + g) * 96 + 64 + ks * 8 + q) * 64], acc[g][1], 0, 0, 0);
      }
    }

    // ---- wave-local h wait: lanes 0-31 poll 8 producers x 4 wave-flags ----
    if (l < 32) {
      const unsigned* pf = hflag + (grp * 32 + ks * 8 + (l >> 2)) * 4 + (l & 3);
      const unsigned want = (unsigned)t;   // h(t-1) posted with value t
      unsigned spins = 0;
      for (;;) {
        unsigned v = poll_l2(pf);
        if (__all((int)(v >= want))) break;
        __builtin_amdgcn_s_sleep(1);
        if (++spins > (1u << 14)) break;             // failsafe: fail loud
      }
    }
    __builtin_amdgcn_sched_barrier(0);

    // ---- h pull: frag q entirely from producer (8ks+q)'s 1KB tile ----
    {
      uint4v ha[8];
#pragma unroll
      for (int q = 0; q < 8; ++q)
        ha[q] = ldg_l2(hslotR + ((size_t)(ks * 8 + q) << 10) + row16 * 64 + kg * 16);
      asm volatile("s_waitcnt vmcnt(0)" ::: "memory");
      __builtin_amdgcn_sched_barrier(0);
#pragma unroll
      for (int q = 0; q < 8; ++q) {
        short8 a = __builtin_bit_cast(short8, ha[q]);
#pragma unroll
        for (int g = 0; g < 4; ++g) {
          acc[g][0] = __builtin_amdgcn_mfma_f32_16x16x32_bf16(a, WH[g][0][q], acc[g][0], 0, 0, 0);
          acc[g][1] = __builtin_amdgcn_mfma_f32_16x16x32_bf16(a, WH[g][1][q], acc[g][1], 0, 0, 0);
        }
      }
    }
#pragma unroll
    for (int g = 0; g < 4; ++g)
#pragma unroll
      for (int T = 0; T < 2; ++T)
#pragma unroll
        for (int i = 0; i < 4; ++i)
          ldsA[ks][g][T][kg * 4 + i][col] = acc[g][T][i];
    __syncthreads();                     // partials ready

    // ---- c_new combine (ALL 256 threads); sc0 store; own-wave drain; flag ----
    {
      float aw0 = bw0r, aw1 = bw1r, af0 = bf0r, af1 = bf1r, ag0 = bc0r, ag1 = bc1r;
#pragma unroll
      for (int k = 0; k < 4; ++k) {
        aw0 += ldsA[k][0][Tc][crow][ci0]; aw1 += ldsA[k][0][Tc][crow][ci1];
        af0 += ldsA[k][1][Tc][crow][ci0]; af1 += ldsA[k][1][Tc][crow][ci1];
        ag0 += ldsA[k][2][Tc][crow][ci0]; ag1 += ldsA[k][2][Tc][crow][ci1];
      }
      float cn0 = sig_fast(af0) * c_reg0 + sig_fast(aw0) * tanh_fast(ag0);
      float cn1 = sig_fast(af1) * c_reg1 + sig_fast(aw1) * tanh_fast(ag1);
      c_reg0 = cn0; c_reg1 = cn1;
      stg_l2(cDstW, pk2(cn0, cn1));
    }
    asm volatile("s_waitcnt vmcnt(0)" ::: "memory");   // own wave's stores at L2
    if (l == 0) stg_l2(cflagP, (unsigned)t + 1u);      // single-writer, monotone

    // ---- gap fillers: prefetch WBo (L2-warm) + stage x(t+1) ----
    short8 WBo[2][8];
#pragma unroll
    for (int T = 0; T < 2; ++T)
#pragma unroll
      for (int q = 0; q < 8; ++q)
        WBo[T][q] = WBl[(size_t)(((pcol * 2 + T) * 4 + ks) * 8 + q) * 64];
    if (t < 511) {
      const float* xs = x + (((size_t)t + 1) << 16) + (size_t)grp * 16384;
#pragma unroll
      for (int i = 0; i < 8; ++i) {
        int q = i * 256 + tid;
        const float* s = xs + q * 8;
        float4 f0 = *(const float4*)s;
        float4 f1 = *(const float4*)(s + 4);
        short8 v;
        v[0] = bfc(f0.x); v[1] = bfc(f0.y); v[2] = bfc(f0.z); v[3] = bfc(f0.w);
        v[4] = bfc(f1.x); v[5] = bfc(f1.y); v[6] = bfc(f1.z); v[7] = bfc(f1.w);
        int rw = q >> 7, kb = (q & 127) ^ (rw & 7);
        *(short8*)(sx + rw * 2048 + (kb << 4)) = v;
      }
    }

    // ---- wave-local c wait: lanes 0-31 poll 8 producers x 4 wave-flags ----
    if (l < 32) {
      const unsigned* pf = cflag + (grp * 32 + ks * 8 + (l >> 2)) * 4 + (l & 3);
      const unsigned want = (unsigned)t + 1u;
      unsigned spins = 0;
      for (;;) {
        unsigned v = poll_l2(pf);
        if (__all((int)(v >= want))) break;
        __builtin_amdgcn_s_sleep(1);
        if (++spins > (1u << 14)) break;             // failsafe: fail loud
      }
    }
    __builtin_amdgcn_sched_barrier(0);

    // ---- phase B: c pull -> MFMA (2 tiles); carry c into sc_ ----
    {
      uint4v ca[8];
#pragma unroll
      for (int q = 0; q < 8; ++q)
        ca[q] = ldg_l2(cslotR + ((size_t)(ks * 8 + q) << 10) + row16 * 64 + kg * 16);
      asm volatile("s_waitcnt vmcnt(0)" ::: "memory");
      __builtin_amdgcn_sched_barrier(0);
      f32x4 b0[2], b1[2];
      b0[0] = (f32x4){0.f, 0.f, 0.f, 0.f}; b0[1] = b0[0];
      b1[0] = b0[0]; b1[1] = b0[0];
#pragma unroll
      for (int q = 0; q < 8; ++q) {
        short8 a = __builtin_bit_cast(short8, ca[q]);
        if (q & 1) {
          b1[0] = __builtin_amdgcn_mfma_f32_16x16x32_bf16(a, WBo[0][q], b1[0], 0, 0, 0);
          b1[1] = __builtin_amdgcn_mfma_f32_16x16x32_bf16(a, WBo[1][q], b1[1], 0, 0, 0);
        } else {
          b0[0] = __builtin_amdgcn_mfma_f32_16x16x32_bf16(a, WBo[0][q], b0[0], 0, 0, 0);
          b0[1] = __builtin_amdgcn_mfma_f32_16x16x32_bf16(a, WBo[1][q], b0[1], 0, 0, 0);
        }
      }
      // carry: wave ks covers its own K-window [256ks,+256) bijectively
#pragma unroll
      for (int q = 0; q < 8; ++q) {
        int kb = 32 * ks + 4 * q + kg;
        *(uint4v*)(sc_ + row16 * 2048 + ((kb ^ srow) << 4)) = ca[q];
      }
#pragma unroll
      for (int T = 0; T < 2; ++T)
#pragma unroll
        for (int i = 0; i < 4; ++i)
          ldsB[ks][T][kg * 4 + i][col] = b0[T][i] + b1[T][i];
    }
    __syncthreads();                     // B-partials ready

    // ---- o combine, h_new (ALL 256); sc0 store; drain; flag; out[] ----
    {
      float s0 = bo0r, s1 = bo1r;
#pragma unroll
      for (int k = 0; k < 4; ++k) {
        s0 += ldsA[k][3][Tc][crow][ci0] + ldsB[k][Tc][crow][ci0];
        s1 += ldsA[k][3][Tc][crow][ci1] + ldsB[k][Tc][crow][ci1];
      }
      float o0 = sig_fast(s0), o1 = sig_fast(s1);
      float h0v = o0 * tanh_fast(c_reg0);
      float h1v = o1 * tanh_fast(c_reg1);
      stg_l2(hDstW, pk2(h0v, h1v));
      asm volatile("s_waitcnt vmcnt(0)" ::: "memory");   // own wave's h at L2
      if (l == 0) stg_l2(hflagP, (unsigned)t + 1u);
      float2 hv; hv.x = h0v; hv.y = h1v;
      *(float2*)(out + ((size_t)t << 16) + coff) = hv;
      if (t == 511) {                    // finals: owner writes directly
        *(float2*)(out + ((size_t)512 << 16) + coff) = hv;
        float2 cv; cv.x = c_reg0; cv.y = c_reg1;
        *(float2*)(out + ((size_t)512 << 16) + 65536 + coff) = cv;
      }
    }
  }
}

extern "C" void kernel_launch(void* const* d_in, const int* in_sizes, int n_in,
                              void* d_out, int out_size, void* d_ws, size_t ws_size,
                              hipStream_t stream) {
  (void)in_sizes; (void)n_in; (void)out_size;
  const float* x  = (const float*)d_in[0];
  const float* h0 = (const float*)d_in[1];
  const float* c0 = (const float*)d_in[2];
  const float* Ww = (const float*)d_in[3];
  const float* bw = (const float*)d_in[4];
  const float* Wf = (const float*)d_in[5];
  const float* bfg= (const float*)d_in[6];
  const float* Wc = (const float*)d_in[7];
  const float* bc = (const float*)d_in[8];
  const float* Wo = (const float*)d_in[9];
  const float* bo = (const float*)d_in[10];

  if (ws_size < (size_t)WS_NEED) return;  // leaves poison -> loud failure

  prep_kernel<<<dim3(2048), dim3(256), 0, stream>>>(h0, c0, Ww, Wf, Wc, Wo,
                                                    (char*)d_ws);
  lstm_kernel<<<dim3(256), dim3(256), 0, stream>>>(x, c0, bw, bfg, bc, bo,
                                                   (float*)d_out, (char*)d_ws);
}

// Round 12
// 4108.031 us; speedup vs baseline: 382.7987x; 382.7987x over previous
//
#include <hip/hip_runtime.h>
#include <hip/hip_bf16.h>
#include <stdint.h>

// ---------------------------------------------------------------------------
// Peephole LSTM, SEQ=512, B=64, I=H=1024.  Persistent-kernel, 256 blocks.
// Round-21: R19 base (verified 5.92ms) + FULL WEIGHT PINNING.
//  * R20 post-mortem: sc0-only comm polls are served STALE from L1 (flag
//    line stays resident); every wait hit the 16K spin cap -> 3.07ms/step.
//    Lesson: cross-CU comm requires sc0 sc1 (L3); no usable L2 scope.
//    R20's structure is abandoned; R19 restored wholesale.
//  * Change: xA (32 frags) + cA (16 frags) weight fragments pinned in
//    registers alongside WH/WBo.  Eliminates ~49MB/step of L3 weight
//    streaming (192KB/block/step x 256 blocks) that contends with every
//    exchange round-trip.  R12 proved post-wait load-burst removal
//    deflates the chain; this removes the remaining self-inflicted L3
//    traffic.  VGPR 208 -> ~400-460 (budget 512 at 1 wave/SIMD).
//  * Everything else byte-identical to R19 (verified).
// ---------------------------------------------------------------------------

typedef __attribute__((ext_vector_type(8))) short short8;
typedef __attribute__((ext_vector_type(4))) float f32x4;
typedef __attribute__((ext_vector_type(4))) unsigned int uint4v;

#define OFF_WB   25165824u   // WA: 64cg*4g*96kc*64l*8e bf16
#define OFF_HBF  27262976u   // WB: 2097152
#define OFF_CBF  27525120u   // hbf: 2 slots * 131072 (slice-grouped)
#define OFF_BAR  27787264u   // cbf: 2 slots * 131072 (slice-grouped)
#define WS_NEED  27918336u   // bar: hflag @0, cflag @ +4096 dwords

__device__ __forceinline__ short bfc(float f) {
  __hip_bfloat16 h = __float2bfloat16(f);
  return *reinterpret_cast<short*>(&h);
}
__device__ __forceinline__ unsigned pk2(float a, float b) {
  __hip_bfloat16 ha = __float2bfloat16(a), hb = __float2bfloat16(b);
  unsigned short ua = *reinterpret_cast<unsigned short*>(&ha);
  unsigned short ub = *reinterpret_cast<unsigned short*>(&hb);
  return (unsigned)ua | ((unsigned)ub << 16);
}
__device__ __forceinline__ float sig_fast(float v) {
  return __fdividef(1.f, 1.f + __expf(-v));
}
__device__ __forceinline__ float tanh_fast(float v) {
  float a = fabsf(v);
  float e = __expf(-2.f * a);
  float t = (1.f - e) * __fdividef(1.f, 1.f + e);
  return copysignf(t, v);
}

// ---- L1+L2-bypassing accesses (coherent at L3 across XCDs) ----
__device__ __forceinline__ uint4v ldg_sc(const void* p) {
  uint4v r;
  asm volatile("global_load_dwordx4 %0, %1, off sc0 sc1" : "=v"(r) : "v"(p));
  return r;
}
__device__ __forceinline__ unsigned poll_sc(const unsigned* p) {
  unsigned r;
  asm volatile("global_load_dword %0, %1, off sc0 sc1\n\ts_waitcnt vmcnt(0)"
               : "=v"(r) : "v"(p) : "memory");
  return r;
}
__device__ __forceinline__ void stg_u32_sc(unsigned* p, unsigned v) {
  asm volatile("global_store_dword %0, %1, off sc0 sc1" :: "v"(p), "v"(v) : "memory");
}

// ---------------------------------------------------------------------------
// prep: pack weights + slice-grouped h0 (slot 0) + zero bar region.
// WA slot ((cg*4+g)*96+kc)*64+l holds W_g[j=cg*16+(l&15)][kc*32+8*(l>>4)+e]
// WB slot ((cg*4+v)*8+kc)*64+l holds Wo[j][2048 + v*256+kc*32+8*(l>>4)+e].
// h slice tile: u32 idx ((grp*64+cg)*128 + r*8 + cpr) = pair (2 bf16).
// ---------------------------------------------------------------------------
#define Z0 1310720LL
#define Z1 131072LL
#define Z2 32768LL
#define Z3 32768LL

__global__ __launch_bounds__(256)
void prep_kernel(const float* __restrict__ h0, const float* __restrict__ c0,
                 const float* __restrict__ Ww, const float* __restrict__ Wf,
                 const float* __restrict__ Wc, const float* __restrict__ Wo,
                 char* __restrict__ ws) {
  __hip_bfloat16* WA  = (__hip_bfloat16*)ws;
  __hip_bfloat16* WB  = (__hip_bfloat16*)(ws + OFF_WB);
  unsigned*     hbf32 = (unsigned*)(ws + OFF_HBF);   // slot 0
  unsigned*       bar = (unsigned*)(ws + OFF_BAR);

  const long long total = Z0 + Z1 + Z2 + Z3;
  for (long long idx = (long long)blockIdx.x * 256 + threadIdx.x; idx < total;
       idx += (long long)gridDim.x * 256) {
    if (idx < Z0) {
      int l  = (int)(idx & 63);
      int s  = (int)((idx >> 6) % 320);
      int cg = (int)(idx / (320 * 64));
      int g, kc;
      if (s < 96)       { g = 0; kc = s; }
      else if (s < 192) { g = 1; kc = s - 96; }
      else if (s < 256) { g = 2; kc = s - 192; }
      else              { g = 3; kc = s - 256; }
      int j  = cg * 16 + (l & 15);
      int kb = kc * 32 + ((l >> 4) << 3);
      const float* W; int rl;
      if (g == 0)      { W = Ww; rl = 3072; }
      else if (g == 1) { W = Wf; rl = 3072; }
      else if (g == 2) { W = Wc; rl = 2048; }
      else             { W = Wo; rl = 3072; }
      const float* src = W + (size_t)j * rl + kb;
      __hip_bfloat16* dst = WA + ((((size_t)cg * 4 + g) * 96 + kc) * 64 + l) * 8;
#pragma unroll
      for (int e = 0; e < 8; ++e) dst[e] = __float2bfloat16(src[e]);
    } else if (idx < Z0 + Z1) {
      long long q = idx - Z0;
      int l  = (int)(q & 63);
      int kc = (int)((q >> 6) & 7);
      int v  = (int)((q >> 9) & 3);
      int cg = (int)(q >> 11);
      int j  = cg * 16 + (l & 15);
      int k  = 2048 + v * 256 + kc * 32 + ((l >> 4) << 3);
      const float* src = Wo + (size_t)j * 3072 + k;
      __hip_bfloat16* dst = WB + ((((size_t)cg * 4 + v) * 8 + kc) * 64 + l) * 8;
#pragma unroll
      for (int e = 0; e < 8; ++e) dst[e] = __float2bfloat16(src[e]);
    } else if (idx < Z0 + Z1 + Z2) {
      int u  = (int)(idx - (Z0 + Z1));        // pair index: R=u>>9, pp=u&511
      int R  = u >> 9, pp = u & 511;
      int cgp = pp >> 3, cprp = pp & 7;
      int dst = ((R >> 4) * 64 + cgp) * 128 + (R & 15) * 8 + cprp;
      const float* hs = h0 + (size_t)R * 1024 + 2 * pp;
      hbf32[dst] = pk2(hs[0], hs[1]);
    } else {
      int i = (int)(idx - (Z0 + Z1 + Z2));
      bar[i] = 0u;
    }
  }
}

// ---------------------------------------------------------------------------
// main persistent kernel
// ---------------------------------------------------------------------------
__global__ __launch_bounds__(256, 1)
void lstm_kernel(const float* __restrict__ x,  const float* __restrict__ c0,
                 const float* __restrict__ bw, const float* __restrict__ bfg,
                 const float* __restrict__ bc, const float* __restrict__ bo,
                 float* __restrict__ out, char* __restrict__ ws) {
  char*     hbf   = ws + OFF_HBF;
  char*     cbf   = ws + OFF_CBF;
  unsigned* hflag = (unsigned*)(ws + OFF_BAR);          // (grp*64+cg)*16
  unsigned* cflag = (unsigned*)(ws + OFF_BAR) + 4096;   // (grp*64+cg)*16

  const int tid  = threadIdx.x;
  const int l    = tid & 63;
  const int wv   = tid >> 6;                         // wave = K-quarter
  const int ks   = wv;
  const int b    = blockIdx.x;
  const int cg   = ((b & 7) << 3) | ((b >> 3) & 7);  // XCD-partitioned col-group
  const int grp  = b >> 6;                           // batch row-group (0..3)
  const int col  = l & 15;
  const int kg   = l >> 4;
  const int row16 = col;                             // A-frag row within tile
  const int srow  = row16 & 7;                       // LDS swizzle key

  // per-gate weight base (this block's 16 columns): gate g at +g*96*64 slots
  const short8* BWb = (const short8*)ws + ((size_t)cg * 4) * 96 * 64 + l;
  const short8* BO  = (const short8*)(ws + OFF_WB) + ((size_t)(cg * 4 + wv)) * 8 * 64 + l;

  __shared__ __align__(16) char sx[32768];   // x tile  [16][1024] bf16, swizzled
  __shared__ __align__(16) char sc_[32768];  // c tile (carried across steps)
  __shared__ float lds[20][16][17];          // [ks*4+g] A-partials | [16+ks] B

  // combine mapping: tid<128 owns (crow, 2 cols)
  const int crow = tid >> 3;
  const int cpr  = tid & 7;
  const int coff = ((grp * 16 + crow) << 10) + (cg << 4) + 2 * cpr;
  float c_reg0 = 0.f, c_reg1 = 0.f;
  float bw0r = 0.f, bw1r = 0.f, bf0r = 0.f, bf1r = 0.f;
  float bc0r = 0.f, bc1r = 0.f, bo0r = 0.f, bo1r = 0.f;
  if (tid < 128) {
    c_reg0 = c0[coff]; c_reg1 = c0[coff + 1];
    int jc = (cg << 4) + 2 * cpr;
    bw0r = bw[jc];  bw1r = bw[jc + 1];
    bf0r = bfg[jc]; bf1r = bfg[jc + 1];
    bc0r = bc[jc];  bc1r = bc[jc + 1];
    bo0r = bo[jc];  bo1r = bo[jc + 1];
  }
  // producer targets (slice-grouped 512B tiles)
  char* hDst = hbf + ((size_t)(grp * 64 + cg)) * 512 + crow * 32 + cpr * 4;
  char* cDst = cbf + ((size_t)(grp * 64 + cg)) * 512 + crow * 32 + cpr * 4;
  unsigned* hflagP = hflag + (grp * 64 + cg) * 16;
  unsigned* cflagP = cflag + (grp * 64 + cg) * 16;

  // ---- startup: stage c0 tile fp32->bf16 -> swizzled sc_ (R13 math) ----
  {
    const float* cs = c0 + (size_t)grp * 16384;
#pragma unroll
    for (int i = 0; i < 8; ++i) {
      int q = i * 256 + tid;
      const float* s = cs + q * 8;
      float4 f0 = *(const float4*)s;
      float4 f1 = *(const float4*)(s + 4);
      short8 v;
      v[0] = bfc(f0.x); v[1] = bfc(f0.y); v[2] = bfc(f0.z); v[3] = bfc(f0.w);
      v[4] = bfc(f1.x); v[5] = bfc(f1.y); v[6] = bfc(f1.z); v[7] = bfc(f1.w);
      int rw = q >> 7, kb = (q & 127) ^ (rw & 7);
      *(short8*)(sc_ + rw * 2048 + (kb << 4)) = v;
    }
  }
  // ---- startup: stage x(0) tile (consumed by xA at t=0) ----
  {
    const float* xs = x + (size_t)grp * 16384;
#pragma unroll
    for (int i = 0; i < 8; ++i) {
      int q = i * 256 + tid;
      const float* s = xs + q * 8;
      float4 f0 = *(const float4*)s;
      float4 f1 = *(const float4*)(s + 4);
      short8 v;
      v[0] = bfc(f0.x); v[1] = bfc(f0.y); v[2] = bfc(f0.z); v[3] = bfc(f0.w);
      v[4] = bfc(f1.x); v[5] = bfc(f1.y); v[6] = bfc(f1.z); v[7] = bfc(f1.w);
      int rw = q >> 7, kb = (q & 127) ^ (rw & 7);
      *(short8*)(sx + rw * 2048 + (kb << 4)) = v;
    }
  }

  // ---- pin ALL loop-invariant weights in registers:
  //      WX[4][8] x-part, WC[2][8] c-part, WH[4][8] h-part, WBo[8] phase-B.
  //      88 frags = 352 VGPR; total ~430 < 512 budget at 1 wave/SIMD. ----
  short8 WX[4][8];
#pragma unroll
  for (int g = 0; g < 4; ++g)
#pragma unroll
    for (int q = 0; q < 8; ++q)
      WX[g][q] = BWb[(size_t)(g * 96 + ks * 8 + q) * 64];
  short8 WC[2][8];
#pragma unroll
  for (int g = 0; g < 2; ++g)
#pragma unroll
    for (int q = 0; q < 8; ++q)
      WC[g][q] = BWb[(size_t)(g * 96 + 64 + ks * 8 + q) * 64];
  short8 WH[4][8];
#pragma unroll
  for (int g = 0; g < 4; ++g)
#pragma unroll
    for (int q = 0; q < 8; ++q)
      WH[g][q] = BWb[(size_t)(g * 96 + 32 + ks * 8 + q) * 64];
  short8 WBo[8];
#pragma unroll
  for (int k = 0; k < 8; ++k) WBo[k] = BO[(size_t)k * 64];

  __syncthreads();                     // startup sx/sc_ visible block-wide

  for (int t = 0; t < 512; ++t) {
    const int p = t & 1;
    const char* hslot = hbf + (size_t)p * 131072 + (size_t)grp * 32768;
    char* cslotW = cbf + (size_t)(p ^ 1) * 131072;   // c_new slot this step

    // loop-top barrier: orders prev-step o-combine partial reads, sx gap
    // writes, sc_ carry writes vs this step's partial writes / LDS reads.
    __syncthreads();

    f32x4 acc[4][2];
#pragma unroll
    for (int g = 0; g < 4; ++g) {
      acc[g][0] = (f32x4){0.f, 0.f, 0.f, 0.f};
      acc[g][1] = (f32x4){0.f, 0.f, 0.f, 0.f};
    }

    // ---- phase A, x part: A-frag loaded once, reused by 4 gates (pinned W) ----
#pragma unroll
    for (int q = 0; q < 8; ++q) {
      int f = ks * 8 + q;
      short8 a = *(const short8*)(sx + row16 * 2048 + ((((f << 2) + kg) ^ srow) << 4));
      acc[0][q & 1] = __builtin_amdgcn_mfma_f32_16x16x32_bf16(a, WX[0][q], acc[0][q & 1], 0, 0, 0);
      acc[1][q & 1] = __builtin_amdgcn_mfma_f32_16x16x32_bf16(a, WX[1][q], acc[1][q & 1], 0, 0, 0);
      acc[2][q & 1] = __builtin_amdgcn_mfma_f32_16x16x32_bf16(a, WX[2][q], acc[2][q & 1], 0, 0, 0);
      acc[3][q & 1] = __builtin_amdgcn_mfma_f32_16x16x32_bf16(a, WX[3][q], acc[3][q & 1], 0, 0, 0);
    }
    // ---- phase A, c part (gates w,f only) — sc_ carries c(t-1) (pinned W) ----
#pragma unroll
    for (int q = 0; q < 8; ++q) {
      int f = ks * 8 + q;
      short8 a = *(const short8*)(sc_ + row16 * 2048 + ((((f << 2) + kg) ^ srow) << 4));
      acc[0][q & 1] = __builtin_amdgcn_mfma_f32_16x16x32_bf16(a, WC[0][q], acc[0][q & 1], 0, 0, 0);
      acc[1][q & 1] = __builtin_amdgcn_mfma_f32_16x16x32_bf16(a, WC[1][q], acc[1][q & 1], 0, 0, 0);
    }

    // ---- WAVE-LOCAL h wait: lanes 0-15 poll this quarter's 16 producers ----
    if (l < 16) {
      const unsigned* pf = hflag + (grp * 64 + ks * 16 + l) * 16;
      const unsigned want = 2u * (unsigned)t;
      unsigned spins = 0;
      for (;;) {
        unsigned v = poll_sc(pf);
        if (__all((int)(v >= want))) break;
        __builtin_amdgcn_s_sleep(1);
        if (++spins > (1u << 18)) break;             // failsafe: fail loud
      }
    }
    __builtin_amdgcn_sched_barrier(0);

    // ---- h pull: 8 fragments direct L3 -> registers (slice-grouped) ----
    {
      const char* hb2 = hslot + row16 * 32 + (kg & 1) * 16;
      const int s0 = ks * 16 + (kg >> 1);
      uint4v ha[8];
#pragma unroll
      for (int q = 0; q < 8; ++q)
        ha[q] = ldg_sc(hb2 + (size_t)(s0 + 2 * q) * 512);
      asm volatile("s_waitcnt vmcnt(0)" ::: "memory");
      __builtin_amdgcn_sched_barrier(0);
      // ---- phase A, h part: 8 frags x 4 gates, register-pinned B ----
#pragma unroll
      for (int q = 0; q < 8; ++q) {
        short8 a = __builtin_bit_cast(short8, ha[q]);
        acc[0][q & 1] = __builtin_amdgcn_mfma_f32_16x16x32_bf16(a, WH[0][q], acc[0][q & 1], 0, 0, 0);
        acc[1][q & 1] = __builtin_amdgcn_mfma_f32_16x16x32_bf16(a, WH[1][q], acc[1][q & 1], 0, 0, 0);
        acc[2][q & 1] = __builtin_amdgcn_mfma_f32_16x16x32_bf16(a, WH[2][q], acc[2][q & 1], 0, 0, 0);
        acc[3][q & 1] = __builtin_amdgcn_mfma_f32_16x16x32_bf16(a, WH[3][q], acc[3][q & 1], 0, 0, 0);
      }
    }
    // ---- write gate partials (per K-quarter) ----
#pragma unroll
    for (int g = 0; g < 4; ++g)
#pragma unroll
      for (int i = 0; i < 4; ++i)
        lds[ks * 4 + g][kg * 4 + i][col] = acc[g][0][i] + acc[g][1][i];
    __syncthreads();                   // partials ready for combine

    // ---- c_new combine (tid<128); slice store; own-wave drain; bump ----
    if (tid < 128) {
      int c0i = 2 * cpr, c1i = 2 * cpr + 1;
      float aw0 = bw0r, aw1 = bw1r, af0 = bf0r, af1 = bf1r, ag0 = bc0r, ag1 = bc1r;
#pragma unroll
      for (int k = 0; k < 4; ++k) {
        aw0 += lds[k * 4 + 0][crow][c0i]; aw1 += lds[k * 4 + 0][crow][c1i];
        af0 += lds[k * 4 + 1][crow][c0i]; af1 += lds[k * 4 + 1][crow][c1i];
        ag0 += lds[k * 4 + 2][crow][c0i]; ag1 += lds[k * 4 + 2][crow][c1i];
      }
      float cn0 = sig_fast(af0) * c_reg0 + sig_fast(aw0) * tanh_fast(ag0);
      float cn1 = sig_fast(af1) * c_reg1 + sig_fast(aw1) * tanh_fast(ag1);
      c_reg0 = cn0; c_reg1 = cn1;
      stg_u32_sc((unsigned*)(cDst + (size_t)(p ^ 1) * 131072), pk2(cn0, cn1));
      asm volatile("s_waitcnt vmcnt(0)" ::: "memory");   // own wave's store at L3
      if (l == 0)
        __hip_atomic_fetch_add(cflagP, 1u,
                               __ATOMIC_RELAXED, __HIP_MEMORY_SCOPE_AGENT);
    }

    // ---- fill the c-exchange gap: stage x(t+1) (sx is dead here) ----
    if (t < 511) {
      const float* xs = x + (((size_t)t + 1) << 16) + (size_t)grp * 16384;
#pragma unroll
      for (int i = 0; i < 8; ++i) {
        int q = i * 256 + tid;
        const float* s = xs + q * 8;
        float4 f0 = *(const float4*)s;
        float4 f1 = *(const float4*)(s + 4);
        short8 v;
        v[0] = bfc(f0.x); v[1] = bfc(f0.y); v[2] = bfc(f0.z); v[3] = bfc(f0.w);
        v[4] = bfc(f1.x); v[5] = bfc(f1.y); v[6] = bfc(f1.z); v[7] = bfc(f1.w);
        int rw = q >> 7, kb = (q & 127) ^ (rw & 7);
        *(short8*)(sx + rw * 2048 + (kb << 4)) = v;
      }
    }

    // ---- WAVE-LOCAL c wait: lanes 0-15 poll this wave's 16 producers ----
    if (l < 16) {
      const unsigned* pf = cflag + (grp * 64 + wv * 16 + l) * 16;
      const unsigned want = 2u * ((unsigned)t + 1u);
      unsigned spins = 0;
      for (;;) {
        unsigned v = poll_sc(pf);
        if (__all((int)(v >= want))) break;
        __builtin_amdgcn_s_sleep(1);
        if (++spins > (1u << 18)) break;             // failsafe: fail loud
      }
    }
    __builtin_amdgcn_sched_barrier(0);

    // ---- phase B: slice-layout c pull (wave-local slices) -> MFMA; carry ----
    {
      const char* cslot = cslotW + (size_t)grp * 32768 + row16 * 32 + (kg & 1) * 16;
      uint4v ca[8];
#pragma unroll
      for (int kcc = 0; kcc < 8; ++kcc) {
        int s = wv * 16 + kcc * 2 + (kg >> 1);
        ca[kcc] = ldg_sc(cslot + (size_t)s * 512);
      }
      asm volatile("s_waitcnt vmcnt(0)" ::: "memory");
      __builtin_amdgcn_sched_barrier(0);
      f32x4 a0 = {0.f, 0.f, 0.f, 0.f}, a1 = {0.f, 0.f, 0.f, 0.f};
#pragma unroll
      for (int kcc = 0; kcc < 8; ++kcc) {
        short8 a = __builtin_bit_cast(short8, ca[kcc]);
        if (kcc & 1) a1 = __builtin_amdgcn_mfma_f32_16x16x32_bf16(a, WBo[kcc], a1, 0, 0, 0);
        else         a0 = __builtin_amdgcn_mfma_f32_16x16x32_bf16(a, WBo[kcc], a0, 0, 0, 0);
      }
      // carry write: unit = wv*32 + kcc*4 + kg (verified bijection over tid)
      const int ub = wv * 32 + kg;
#pragma unroll
      for (int kcc = 0; kcc < 8; ++kcc)
        *(uint4v*)(sc_ + row16 * 2048 + (((ub + kcc * 4) ^ srow) << 4)) = ca[kcc];
#pragma unroll
      for (int i = 0; i < 4; ++i)
        lds[16 + wv][kg * 4 + i][col] = a0[i] + a1[i];
    }
    __syncthreads();                   // phase-B partials ready

    // ---- o combine, h_new; slice store; own-wave drain; bump; out[] ----
    if (tid < 128) {
      int c0i = 2 * cpr, c1i = 2 * cpr + 1;
      float s0 = bo0r, s1 = bo1r;
#pragma unroll
      for (int k = 0; k < 4; ++k) {
        s0 += lds[k * 4 + 3][crow][c0i] + lds[16 + k][crow][c0i];
        s1 += lds[k * 4 + 3][crow][c1i] + lds[16 + k][crow][c1i];
      }
      float o0 = sig_fast(s0), o1 = sig_fast(s1);
      float h0v = o0 * tanh_fast(c_reg0);
      float h1v = o1 * tanh_fast(c_reg1);
      stg_u32_sc((unsigned*)(hDst + (size_t)(p ^ 1) * 131072), pk2(h0v, h1v));
      asm volatile("s_waitcnt vmcnt(0)" ::: "memory");   // own wave's h at L3
      if (l == 0)
        __hip_atomic_fetch_add(hflagP, 1u,
                               __ATOMIC_RELAXED, __HIP_MEMORY_SCOPE_AGENT);
      float2 hv; hv.x = h0v; hv.y = h1v;
      *(float2*)(out + ((size_t)t << 16) + coff) = hv;
      if (t == 511) {                    // finals: owner writes directly
        *(float2*)(out + ((size_t)512 << 16) + coff) = hv;
        float2 cv; cv.x = c_reg0; cv.y = c_reg1;
        *(float2*)(out + ((size_t)512 << 16) + 65536 + coff) = cv;
      }
    }
  }
}

extern "C" void kernel_launch(void* const* d_in, const int* in_sizes, int n_in,
                              void* d_out, int out_size, void* d_ws, size_t ws_size,
                              hipStream_t stream) {
  (void)in_sizes; (void)n_in; (void)out_size;
  const float* x  = (const float*)d_in[0];
  const float* h0 = (const float*)d_in[1];
  const float* c0 = (const float*)d_in[2];
  const float* Ww = (const float*)d_in[3];
  const float* bw = (const float*)d_in[4];
  const float* Wf = (const float*)d_in[5];
  const float* bfg= (const float*)d_in[6];
  const float* Wc = (const float*)d_in[7];
  const float* bc = (const float*)d_in[8];
  const float* Wo = (const float*)d_in[9];
  const float* bo = (const float*)d_in[10];

  if (ws_size < (size_t)WS_NEED) return;  // leaves poison -> loud failure

  prep_kernel<<<dim3(2048), dim3(256), 0, stream>>>(h0, c0, Ww, Wf, Wc, Wo,
                                                    (char*)d_ws);
  lstm_kernel<<<dim3(256), dim3(256), 0, stream>>>(x, c0, bw, bfg, bc, bo,
                                                   (float*)d_out, (char*)d_ws);
}